// Round 13
// baseline (472.687 us; speedup 1.0000x reference)
//
#include <hip/hip_runtime.h>

#define NN 50000
#define NE 800000
#define CAP 64          // padded CSR slots per node (max deg_in ~40 for Poisson(16))

typedef unsigned short u16;
typedef __attribute__((ext_vector_type(8))) short bf8_t;   // 8 x bf16 (4 VGPRs)
typedef __attribute__((ext_vector_type(4))) float f4_t;    // 4 x f32 acc

__device__ __forceinline__ u16 f2b(float f) {              // RNE fp32 -> bf16
    unsigned u = __float_as_uint(f);
    unsigned r = u + 0x7FFF + ((u >> 16) & 1);
    return (u16)(r >> 16);
}

// ---------------- fused build: padded-CSR fill + deg_out count ----------------
__global__ void build_k(const int* __restrict__ src, const int* __restrict__ dst,
                        int* __restrict__ cursor_in, int* __restrict__ deg_out,
                        int2* __restrict__ csr, int E) {
    int e = blockIdx.x * 256 + threadIdx.x;
    if (e < E) {
        int s = src[e];
        int d = dst[e];
        int p = atomicAdd(cursor_in + d, 1);
        csr[(d << 6) + p] = make_int2(s, e);
        atomicAdd(deg_out + s, 1);
    }
}

__global__ void make_inv_k(const int* __restrict__ deg_in, const int* __restrict__ deg_out,
                           float* __restrict__ inv_in, float* __restrict__ inv_out,
                           float* __restrict__ inv_mean, float* __restrict__ bcoef, int n) {
    int i = blockIdx.x * 256 + threadIdx.x;
    if (i < n) {
        int d_in = deg_in[i];
        float di = fmaxf((float)d_in, 1.0f);
        float dq = fmaxf((float)deg_out[i], 1.0f);
        inv_in[i]   = 1.0f / sqrtf(di);
        inv_out[i]  = 1.0f / sqrtf(dq);
        inv_mean[i] = 1.0f / di;
        bcoef[i]    = (d_in > 0) ? 1.0f : 0.0f;
    }
}

// ---------------- fp32 edge-feat gather: 2 nodes/block, 4-way edge split ----------------
// unit u = wave*2 + lanehalf owns 4-slot windows at stride 16.
__global__ __launch_bounds__(256) void gather_e3_k(
    const float* __restrict__ ef, const int2* __restrict__ csr,
    const int* __restrict__ deg, float* __restrict__ efa) {
    __shared__ float ep[2][32];
    const int lane = threadIdx.x & 63;
    const int slot = threadIdx.x >> 7;         // node slot in block (0/1)
    const int wh = (threadIdx.x >> 6) & 1;     // wave within pair
    const int node = __builtin_amdgcn_readfirstlane(blockIdx.x * 2 + slot);
    const int beg = node << 6;
    const int cnt = deg[node];
    const int off = lane & 31;
    const int u = wh * 2 + (lane >> 5);
    float acc = 0.0f;

    for (int base = u * 4; base + 4 <= cnt; base += 16) {
        int idx[4];
#pragma unroll
        for (int j = 0; j < 4; ++j) idx[j] = csr[beg + base + j].y;
        float lv[4];
#pragma unroll
        for (int j = 0; j < 4; ++j) lv[j] = ef[(size_t)idx[j] * 32 + off];
#pragma unroll
        for (int j = 0; j < 4; ++j) acc += lv[j];
    }
    {
        const int tb = cnt & ~3, tc = cnt & 3;
        if (tc && ((tb >> 2) & 3) == u)
            for (int t = 0; t < tc; ++t) acc += ef[(size_t)csr[beg + tb + t].y * 32 + off];
    }

    acc += __shfl_down(acc, 32);               // combine lane halves
    if (wh == 0 && lane < 32) ep[slot][lane] = acc;
    __syncthreads();
    if (wh == 1 && lane < 32) efa[(size_t)node * 32 + lane] = acc + ep[slot][lane];
}

// ---------------- bf16 gather: 2 nodes/block, 2 waves/node, 8-deep batches ----------------
// agg[d] = bf16( inv_in[d] * sum_e h[src_e] );  h pre-scaled by inv_out.
// wave wh owns 8-slot windows at stride 16; partials combined via LDS.
template <int D, int LPT>
__global__ __launch_bounds__(256) void gather_b3_k(
    const u16* __restrict__ h, const int2* __restrict__ csr,
    const int* __restrict__ deg, const float* __restrict__ inv_in,
    u16* __restrict__ agg) {
    constexpr int ACT = D / LPT;
    constexpr int NW = LPT / 2;          // uints per lane-load
    __shared__ float part[2][D];
    const int lane = threadIdx.x & 63;
    const int slot = threadIdx.x >> 7;
    const int wh = (threadIdx.x >> 6) & 1;
    const int node = __builtin_amdgcn_readfirstlane(blockIdx.x * 2 + slot);
    const int beg = node << 6;
    const int cnt = deg[node];
    const int off = (lane < ACT ? lane : ACT - 1) * LPT;

    float acc[LPT];
#pragma unroll
    for (int j = 0; j < LPT; ++j) acc[j] = 0.0f;

    for (int base = wh * 8; base + 8 <= cnt; base += 16) {
        int idx[8];
#pragma unroll
        for (int j = 0; j < 8; ++j) idx[j] = csr[beg + base + j].x;
        unsigned lv[8][NW];
#pragma unroll
        for (int j = 0; j < 8; ++j) {
            const unsigned* p = (const unsigned*)(h + (size_t)idx[j] * D + off);
            if constexpr (NW == 2) {
                uint2 t = *(const uint2*)p;
                lv[j][0] = t.x; lv[j][1] = t.y;
            } else {
                lv[j][0] = *p;
            }
        }
#pragma unroll
        for (int j = 0; j < 8; ++j)
#pragma unroll
            for (int q = 0; q < NW; ++q) {
                unsigned u = lv[j][q];
                acc[2 * q]     += __uint_as_float(u << 16);
                acc[2 * q + 1] += __uint_as_float(u & 0xffff0000u);
            }
    }
    {
        const int tb = cnt & ~7, tc = cnt & 7;
        if (tc && ((tb >> 3) & 1) == wh) {
            for (int t = 0; t < tc; ++t) {
                const unsigned* p = (const unsigned*)(h + (size_t)csr[beg + tb + t].x * D + off);
#pragma unroll
                for (int q = 0; q < NW; ++q) {
                    unsigned u = p[q];
                    acc[2 * q]     += __uint_as_float(u << 16);
                    acc[2 * q + 1] += __uint_as_float(u & 0xffff0000u);
                }
            }
        }
    }

    if (wh == 0 && lane < ACT) {
#pragma unroll
        for (int j = 0; j < LPT; ++j) part[slot][lane * LPT + j] = acc[j];
    }
    __syncthreads();
    if (wh == 1 && lane < ACT) {
        float sc = inv_in[node];
        unsigned o[NW];
#pragma unroll
        for (int q = 0; q < NW; ++q) {
            float v0 = (acc[2 * q]     + part[slot][lane * LPT + 2 * q])     * sc;
            float v1 = (acc[2 * q + 1] + part[slot][lane * LPT + 2 * q + 1]) * sc;
            o[q] = (unsigned)f2b(v0) | ((unsigned)f2b(v1) << 16);
        }
        unsigned* dp = (unsigned*)(agg + (size_t)node * D + off);
        if constexpr (NW == 2) {
            uint2 t; t.x = o[0]; t.y = o[1];
            *(uint2*)dp = t;
        } else {
            *dp = o[0];
        }
    }
}

// ---------------- small tiled GEMM (32->32 and 64->96), bf16 output -------------------
template <int D_IN, int D_OUT, bool SCALE, bool BROW>
__global__ __launch_bounds__(256) void gemm_tile_k(
    const float* __restrict__ in, int in_stride,
    const float* __restrict__ W, const float* __restrict__ bias,
    const float* __restrict__ scale, const float* __restrict__ brow,
    const float* __restrict__ posts,
    u16* __restrict__ out, int out_stride, int n) {
    constexpr int TMW = 8;
    constexpr int ROWS = TMW * 4;
    constexpr int NOUT = (D_OUT + 63) / 64;
    __shared__ float s_in[ROWS * D_IN];

    const int tid = threadIdx.x;
    const int lane = tid & 63;
    const int wave = tid >> 6;
    const int row0 = blockIdx.x * ROWS;

    constexpr int NV = ROWS * D_IN / 4;
    for (int i = tid; i < NV; i += 256) {
        int m = i / (D_IN / 4);
        int kv = i % (D_IN / 4);
        int row = min(row0 + m, n - 1);
        float4 v = *(const float4*)(in + (size_t)row * in_stride + kv * 4);
        if (SCALE) {
            float s = scale[row];
            v.x *= s; v.y *= s; v.z *= s; v.w *= s;
        }
        *(float4*)(s_in + m * D_IN + kv * 4) = v;
    }
    __syncthreads();

    int f[NOUT], ff[NOUT];
    bool fok[NOUT];
    float bv[NOUT];
#pragma unroll
    for (int o = 0; o < NOUT; ++o) {
        f[o] = lane + 64 * o;
        fok[o] = (f[o] < D_OUT);
        ff[o] = fok[o] ? f[o] : 0;
        bv[o] = bias[ff[o]];
    }

    const float* s_my = s_in + wave * TMW * D_IN;

    float acc[NOUT][TMW];
#pragma unroll
    for (int o = 0; o < NOUT; ++o)
#pragma unroll
        for (int m = 0; m < TMW; ++m) acc[o][m] = 0.0f;

    for (int k = 0; k < D_IN; k += 4) {
        float w[4][NOUT];
#pragma unroll
        for (int j = 0; j < 4; ++j)
#pragma unroll
            for (int o = 0; o < NOUT; ++o) w[j][o] = W[(k + j) * D_OUT + ff[o]];
#pragma unroll
        for (int m = 0; m < TMW; ++m) {
            float4 a = *(const float4*)(s_my + m * D_IN + k);
#pragma unroll
            for (int o = 0; o < NOUT; ++o) {
                acc[o][m] = fmaf(a.x, w[0][o], acc[o][m]);
                acc[o][m] = fmaf(a.y, w[1][o], acc[o][m]);
                acc[o][m] = fmaf(a.z, w[2][o], acc[o][m]);
                acc[o][m] = fmaf(a.w, w[3][o], acc[o][m]);
            }
        }
    }

#pragma unroll
    for (int m = 0; m < TMW; ++m) {
        int row = row0 + wave * TMW + m;
        if (row < n) {
            float bc = BROW ? brow[row] : 1.0f;
            float pm = posts[row];
#pragma unroll
            for (int o = 0; o < NOUT; ++o) {
                if (!fok[o]) continue;
                float v = fmaxf(acc[o][m] + bv[o] * bc, 0.0f) * pm;
                out[(size_t)row * out_stride + f[o]] = f2b(v);
            }
        }
    }
}

// ---------------- pack W (fp32 [K][192]) into MFMA B-fragment order, bf16 ---------------
template <int K>
__global__ void pack_w_k(const float* __restrict__ W, u16* __restrict__ Wp) {
    constexpr int KS = K / 32;
    int idx = blockIdx.x * 256 + threadIdx.x;
    if (idx >= 12 * KS * 64) return;
    int l = idx & 63;
    int s = (idx >> 6) % KS;
    int t = (idx >> 6) / KS;
    int col = t * 16 + (l & 15);
    int krow = s * 32 + ((l >> 4) * 8);
    u16 tmp[8] __attribute__((aligned(16)));
#pragma unroll
    for (int j = 0; j < 8; ++j) tmp[j] = f2b(W[(size_t)(krow + j) * 192 + col]);
    *(uint4*)(Wp + (size_t)idx * 8) = *(const uint4*)tmp;
}

// ---------------- MFMA GEMM (conv0): h1 = bf16( relu(A@W + b) * inv_out ) ----------------
template <int K>
__global__ __launch_bounds__(256) void mfma_gemm_k(
    const u16* __restrict__ A, const u16* __restrict__ Wp,
    const float* __restrict__ bias, const float* __restrict__ posts,
    u16* __restrict__ outB, int n) {
    constexpr int KS = K / 32;
    const int tid = threadIdx.x;
    const int lane = tid & 63;
    const int w = tid >> 6;
    const int row0 = blockIdx.x * 16;
    const int arow = row0 + (lane & 15);
    const int kbase = (lane >> 4) * 8;

    f4_t acc[3];
#pragma unroll
    for (int o = 0; o < 3; ++o) acc[o] = (f4_t){0.f, 0.f, 0.f, 0.f};

    const u16* ap = A + (size_t)arow * K + kbase;
#pragma unroll
    for (int s = 0; s < KS; ++s) {
        bf8_t af = *(const bf8_t*)(ap + s * 32);
#pragma unroll
        for (int o = 0; o < 3; ++o) {
            int t = w * 3 + o;
            bf8_t bf = *(const bf8_t*)(Wp + (size_t)((t * KS + s) * 64 + lane) * 8);
            acc[o] = __builtin_amdgcn_mfma_f32_16x16x32_bf16(af, bf, acc[o], 0, 0, 0);
        }
    }

    const int drow = row0 + (lane >> 4) * 4;
    const int dcol = lane & 15;
    float pm[4];
#pragma unroll
    for (int r = 0; r < 4; ++r) pm[r] = posts[drow + r];
#pragma unroll
    for (int o = 0; o < 3; ++o) {
        int col = (w * 3 + o) * 16 + dcol;
        float bv = bias[col];
#pragma unroll
        for (int r = 0; r < 4; ++r) {
            float v = fmaxf(acc[o][r] + bv, 0.0f) * pm[r];
            outB[(size_t)(drow + r) * 192 + col] = f2b(v);
        }
    }
}

// ---------------- fused MFMA: conv1 GEMM + linear GEMM + head (192->192->192->2) ---------
__global__ __launch_bounds__(256) void mfma_fused_k(
    const u16* __restrict__ A,  // [n,192] bf16 (inv_in pre-scaled)
    const u16* __restrict__ Wp1, const float* __restrict__ b1,
    const u16* __restrict__ Wp2, const float* __restrict__ b2,
    const float* __restrict__ Wo, const float* __restrict__ bo,
    float* __restrict__ out, int n) {
    constexpr int KS = 6;       // 192/32
    constexpr int S = 200;      // LDS row stride
    __shared__ float sbuf[16 * S];
    __shared__ float s_head[16][17][2];

    const int tid = threadIdx.x;
    const int lane = tid & 63;
    const int w = tid >> 6;
    const int row0 = blockIdx.x * 16;
    const int arow = row0 + (lane & 15);
    const int kbase = (lane >> 4) * 8;
    const int drow = (lane >> 4) * 4;
    const int dcol = lane & 15;

    f4_t acc[3];
#pragma unroll
    for (int o = 0; o < 3; ++o) acc[o] = (f4_t){0.f, 0.f, 0.f, 0.f};

    // ---- GEMM 1: A (global bf16) @ W1 ----
    const u16* ap = A + (size_t)arow * 192 + kbase;
#pragma unroll
    for (int s = 0; s < KS; ++s) {
        bf8_t af = *(const bf8_t*)(ap + s * 32);
#pragma unroll
        for (int o = 0; o < 3; ++o) {
            int t = w * 3 + o;
            bf8_t bf = *(const bf8_t*)(Wp1 + (size_t)((t * KS + s) * 64 + lane) * 8);
            acc[o] = __builtin_amdgcn_mfma_f32_16x16x32_bf16(af, bf, acc[o], 0, 0, 0);
        }
    }

    // h2 = relu(acc + b1) -> LDS (bf16)
    u16* h2 = (u16*)sbuf;
#pragma unroll
    for (int o = 0; o < 3; ++o) {
        int col = (w * 3 + o) * 16 + dcol;
        float bv = b1[col];
#pragma unroll
        for (int r = 0; r < 4; ++r)
            h2[(drow + r) * S + col] = f2b(fmaxf(acc[o][r] + bv, 0.0f));
    }
    __syncthreads();

    // ---- GEMM 2: h2 (LDS bf16) @ W2 ----
#pragma unroll
    for (int o = 0; o < 3; ++o) acc[o] = (f4_t){0.f, 0.f, 0.f, 0.f};
    const u16* hp = h2 + (lane & 15) * S + kbase;
#pragma unroll
    for (int s = 0; s < KS; ++s) {
        bf8_t af = *(const bf8_t*)(hp + s * 32);
#pragma unroll
        for (int o = 0; o < 3; ++o) {
            int t = w * 3 + o;
            bf8_t bf = *(const bf8_t*)(Wp2 + (size_t)((t * KS + s) * 64 + lane) * 8);
            acc[o] = __builtin_amdgcn_mfma_f32_16x16x32_bf16(af, bf, acc[o], 0, 0, 0);
        }
    }
    __syncthreads();  // all h2 reads done before overwriting sbuf as f32

    // h3 = relu(acc + b2) -> LDS (f32)
#pragma unroll
    for (int o = 0; o < 3; ++o) {
        int col = (w * 3 + o) * 16 + dcol;
        float bv = b2[col];
#pragma unroll
        for (int r = 0; r < 4; ++r)
            sbuf[(drow + r) * S + col] = fmaxf(acc[o][r] + bv, 0.0f);
    }
    __syncthreads();

    // ---- head: out = h3 @ Wo + bo ----
    {
        int r = tid >> 4;
        int seg = tid & 15;
        const float* hr = sbuf + r * S + seg * 12;
        const float* wor = Wo + seg * 24;
        float p0 = 0.0f, p1 = 0.0f;
#pragma unroll
        for (int c = 0; c < 12; ++c) {
            float hv = hr[c];
            p0 = fmaf(hv, wor[c * 2 + 0], p0);
            p1 = fmaf(hv, wor[c * 2 + 1], p1);
        }
        s_head[r][seg][0] = p0;
        s_head[r][seg][1] = p1;
    }
    __syncthreads();
    if (tid < 32) {
        int r = tid >> 1, c = tid & 1;
        float sum = bo[c];
#pragma unroll
        for (int g = 0; g < 16; ++g) sum += s_head[r][g][c];
        int row = row0 + r;
        if (row < n) out[(size_t)row * 2 + c] = sum;
    }
}

extern "C" void kernel_launch(void* const* d_in, const int* in_sizes, int n_in,
                              void* d_out, int out_size, void* d_ws, size_t ws_size,
                              hipStream_t stream) {
    const float* node_feats = (const float*)d_in[0];   // [N,64]
    const float* edge_feats = (const float*)d_in[1];   // [E,32]
    const float* Wn  = (const float*)d_in[2];          // [64,96]
    const float* bn  = (const float*)d_in[3];
    const float* We  = (const float*)d_in[4];          // [32,32]
    const float* be  = (const float*)d_in[5];
    const float* Wc0 = (const float*)d_in[6];          // [128,192]
    const float* bc0 = (const float*)d_in[7];
    const float* Wc1 = (const float*)d_in[8];          // [192,192]
    const float* bc1 = (const float*)d_in[9];
    const float* Wl0 = (const float*)d_in[10];         // [192,192]
    const float* bl0 = (const float*)d_in[11];
    const float* Wo  = (const float*)d_in[12];         // [192,2]
    const float* bo  = (const float*)d_in[13];
    const int* src = (const int*)d_in[14];
    const int* dst = (const int*)d_in[15];
    float* out = (float*)d_out;

    const int N = NN, E = NE;

    // ---- workspace layout (16B-aligned sections) ----
    int* din       = (int*)d_ws;               // N (zeroed) -> cursor_in / deg_in
    int* dout      = din + N;                  // N (zeroed) -> deg_out
    int2* csr      = (int2*)(dout + N);        // CAP*N pairs {src, eid} (padded CSR)
    float* inv_in   = (float*)(csr + (size_t)CAP * N);  // N
    float* inv_out  = inv_in + N;              // N
    float* inv_mean = inv_out + N;             // N
    float* bcoef    = inv_mean + N;            // N
    float* efa      = bcoef + N;               // 32N
    u16* h0   = (u16*)(efa + (size_t)32 * N);  // [N,128] bf16 (x inv_out)
    u16* aggA = h0 + (size_t)128 * N;          // [N,128] bf16 (x inv_in)
    u16* h1   = aggA + (size_t)128 * N;        // [N,192] bf16 (x inv_out)
    u16* aggB = h1 + (size_t)192 * N;          // [N,192] bf16 (x inv_in)
    u16* Wp0  = aggB + (size_t)192 * N;        // 128*192
    u16* Wp1  = Wp0 + 128 * 192;               // 192*192
    u16* Wp2  = Wp1 + 192 * 192;               // 192*192

    hipMemsetAsync(d_ws, 0, (size_t)2 * N * sizeof(int), stream);

    const int GB32 = (N + 31) / 32;   // small-GEMM grid
    const int GB16 = N / 16;          // mfma grid (3125, exact)
    const int GN2  = N / 2;           // 2-nodes-per-block gather grid (25000)

    // weight packing (tiny, every launch)
    pack_w_k<128><<<dim3(12), dim3(256), 0, stream>>>(Wc0, Wp0);
    pack_w_k<192><<<dim3(18), dim3(256), 0, stream>>>(Wc1, Wp1);
    pack_w_k<192><<<dim3(18), dim3(256), 0, stream>>>(Wl0, Wp2);

    // one-pass build: padded CSR + deg_out
    build_k<<<dim3((E + 255) / 256), dim3(256), 0, stream>>>(src, dst, din, dout, csr, E);
    make_inv_k<<<dim3((N + 255) / 256), dim3(256), 0, stream>>>(din, dout, inv_in, inv_out,
                                                                inv_mean, bcoef, N);

    // edge aggregation: efa = segment_sum(edge_feats, dst)  (fp32)
    gather_e3_k<<<dim3(GN2), dim3(256), 0, stream>>>(edge_feats, csr, din, efa);
    // h0[:,0:32] = bf16( relu((efa*inv_mean)@We + bcoef*be) * inv_out )
    gemm_tile_k<32, 32, true, true><<<dim3(GB32), dim3(256), 0, stream>>>(
        efa, 32, We, be, inv_mean, bcoef, inv_out, h0, 128, N);
    // h0[:,32:128] = bf16( relu(node_feats@Wn + bn) * inv_out )
    gemm_tile_k<64, 96, false, false><<<dim3(GB32), dim3(256), 0, stream>>>(
        node_feats, 64, Wn, bn, nullptr, nullptr, inv_out, h0 + 32, 128, N);

    // conv0: bf16 gather h0 -> aggA (x inv_in), MFMA GEMM 128->192 -> h1 (x inv_out)
    gather_b3_k<128, 2><<<dim3(GN2), dim3(256), 0, stream>>>(h0, csr, din, inv_in, aggA);
    mfma_gemm_k<128><<<dim3(GB16), dim3(256), 0, stream>>>(aggA, Wp0, bc0, inv_out, h1, N);

    // conv1: bf16 gather h1 -> aggB (x inv_in), fused MFMA (conv1 + linear + head) -> out
    gather_b3_k<192, 4><<<dim3(GN2), dim3(256), 0, stream>>>(h1, csr, din, inv_in, aggB);
    mfma_fused_k<<<dim3(GB16), dim3(256), 0, stream>>>(aggB, Wp1, bc1, Wp2, bl0, Wo, bo,
                                                       out, N);
}

// Round 14
// 455.843 us; speedup vs baseline: 1.0369x; 1.0369x over previous
//
#include <hip/hip_runtime.h>

#define NN 50000
#define NE 800000
#define CAP 64          // padded CSR slots per node (max deg_in ~40 for Poisson(16))

typedef unsigned short u16;
typedef __attribute__((ext_vector_type(8))) short bf8_t;   // 8 x bf16 (4 VGPRs)
typedef __attribute__((ext_vector_type(4))) float f4_t;    // 4 x f32 acc

__device__ __forceinline__ u16 f2b(float f) {              // RNE fp32 -> bf16
    unsigned u = __float_as_uint(f);
    unsigned r = u + 0x7FFF + ((u >> 16) & 1);
    return (u16)(r >> 16);
}

// ---------------- fused build: padded-CSR fill + deg_out count ----------------
__global__ void build_k(const int* __restrict__ src, const int* __restrict__ dst,
                        int* __restrict__ cursor_in, int* __restrict__ deg_out,
                        int2* __restrict__ csr, int E) {
    int e = blockIdx.x * 256 + threadIdx.x;
    if (e < E) {
        int s = src[e];
        int d = dst[e];
        int p = atomicAdd(cursor_in + d, 1);
        csr[(d << 6) + p] = make_int2(s, e);
        atomicAdd(deg_out + s, 1);
    }
}

__global__ void make_inv_k(const int* __restrict__ deg_in, const int* __restrict__ deg_out,
                           float* __restrict__ inv_in, float* __restrict__ inv_out,
                           float* __restrict__ inv_mean, float* __restrict__ bcoef, int n) {
    int i = blockIdx.x * 256 + threadIdx.x;
    if (i < n) {
        int d_in = deg_in[i];
        float di = fmaxf((float)d_in, 1.0f);
        float dq = fmaxf((float)deg_out[i], 1.0f);
        inv_in[i]   = 1.0f / sqrtf(di);
        inv_out[i]  = 1.0f / sqrtf(dq);
        inv_mean[i] = 1.0f / di;
        bcoef[i]    = (d_in > 0) ? 1.0f : 0.0f;
    }
}

// ---------------- fp32 edge-feat gather: wave-per-node, 2 edges/iter via lane halves -----
__global__ __launch_bounds__(256) void gather_e2_k(
    const float* __restrict__ ef, const int2* __restrict__ csr,
    const int* __restrict__ deg, float* __restrict__ efa) {
    const int lane = threadIdx.x & 63;
    const int node = __builtin_amdgcn_readfirstlane(blockIdx.x * 4 + (threadIdx.x >> 6));
    const int beg = node << 6;
    const int cnt = deg[node];
    const int off = lane & 31;
    const int half = lane >> 5;
    float acc = 0.0f;

    const int np = cnt >> 1;           // pairs
    const int nb = np >> 3, rem = np & 7;
    int idx[8];
    if (nb > 0) {
#pragma unroll
        for (int j = 0; j < 8; ++j) idx[j] = csr[beg + 2 * j + half].y;
    }
    for (int b = 0; b < nb; ++b) {
        float lv[8];
#pragma unroll
        for (int j = 0; j < 8; ++j) lv[j] = ef[(size_t)idx[j] * 32 + off];
        int nidx[8];
        const int nbase = beg + 2 * (b + 1) * 8;
        if (b + 1 < nb) {
#pragma unroll
            for (int j = 0; j < 8; ++j) nidx[j] = csr[nbase + 2 * j + half].y;
        }
#pragma unroll
        for (int j = 0; j < 8; ++j) acc += lv[j];
        if (b + 1 < nb) {
#pragma unroll
            for (int j = 0; j < 8; ++j) idx[j] = nidx[j];
        }
    }
    const int tbase = beg + 2 * nb * 8;
    for (int t = 0; t < rem; ++t) acc += ef[(size_t)csr[tbase + 2 * t + half].y * 32 + off];
    if ((cnt & 1) && half == 0) acc += ef[(size_t)csr[beg + cnt - 1].y * 32 + off];

    acc += __shfl_down(acc, 32);
    if (lane < 32) efa[(size_t)node * 32 + off] = acc;
}

// ---------------- bf16 gather, wave-per-node, 16-deep batches ----------------
// agg[d] = bf16( inv_in[d] * sum_e h[src_e] );  h pre-scaled by inv_out.
// Typical node (deg<=16): indices + rows each issue as ONE batch -> 1 latency round-trip.
// Accumulation order = ascending slot (bitwise-identical to 8-deep version).
template <int D, int LPT>
__global__ __launch_bounds__(256) void gather_b2_k(
    const u16* __restrict__ h, const int2* __restrict__ csr,
    const int* __restrict__ deg, const float* __restrict__ inv_in,
    u16* __restrict__ agg) {
    constexpr int ACT = D / LPT;
    constexpr int NW = LPT / 2;          // uints per lane-load
    const int lane = threadIdx.x & 63;
    const int node = __builtin_amdgcn_readfirstlane(blockIdx.x * 4 + (threadIdx.x >> 6));
    const int beg = node << 6;
    const int cnt = deg[node];
    const int off = (lane < ACT ? lane : ACT - 1) * LPT;

    float acc[LPT];
#pragma unroll
    for (int j = 0; j < LPT; ++j) acc[j] = 0.0f;

    // ---- 16-deep batches ----
    const int nb = cnt >> 4;
    int idx[16];
    if (nb > 0) {
#pragma unroll
        for (int j = 0; j < 16; ++j) idx[j] = csr[beg + j].x;
    }
    for (int b = 0; b < nb; ++b) {
        unsigned lv[16][NW];
#pragma unroll
        for (int j = 0; j < 16; ++j) {
            const unsigned* p = (const unsigned*)(h + (size_t)idx[j] * D + off);
            if constexpr (NW == 2) {
                uint2 t = *(const uint2*)p;
                lv[j][0] = t.x; lv[j][1] = t.y;
            } else {
                lv[j][0] = *p;
            }
        }
        int nidx[16];
        const int nbase = beg + (b + 1) * 16;
        if (b + 1 < nb) {
#pragma unroll
            for (int j = 0; j < 16; ++j) nidx[j] = csr[nbase + j].x;
        }
#pragma unroll
        for (int j = 0; j < 16; ++j)
#pragma unroll
            for (int q = 0; q < NW; ++q) {
                unsigned u = lv[j][q];
                acc[2 * q]     += __uint_as_float(u << 16);
                acc[2 * q + 1] += __uint_as_float(u & 0xffff0000u);
            }
        if (b + 1 < nb) {
#pragma unroll
            for (int j = 0; j < 16; ++j) idx[j] = nidx[j];
        }
    }

    // ---- tail: one 8-deep batch, then scalar ----
    int tb = beg + (nb << 4);
    int rem = cnt & 15;
    if (rem >= 8) {
        int ti[8];
#pragma unroll
        for (int j = 0; j < 8; ++j) ti[j] = csr[tb + j].x;
        unsigned lv[8][NW];
#pragma unroll
        for (int j = 0; j < 8; ++j) {
            const unsigned* p = (const unsigned*)(h + (size_t)ti[j] * D + off);
            if constexpr (NW == 2) {
                uint2 t = *(const uint2*)p;
                lv[j][0] = t.x; lv[j][1] = t.y;
            } else {
                lv[j][0] = *p;
            }
        }
#pragma unroll
        for (int j = 0; j < 8; ++j)
#pragma unroll
            for (int q = 0; q < NW; ++q) {
                unsigned u = lv[j][q];
                acc[2 * q]     += __uint_as_float(u << 16);
                acc[2 * q + 1] += __uint_as_float(u & 0xffff0000u);
            }
        tb += 8;
        rem -= 8;
    }
    for (int t = 0; t < rem; ++t) {
        const unsigned* p = (const unsigned*)(h + (size_t)csr[tb + t].x * D + off);
#pragma unroll
        for (int q = 0; q < NW; ++q) {
            unsigned u = p[q];
            acc[2 * q]     += __uint_as_float(u << 16);
            acc[2 * q + 1] += __uint_as_float(u & 0xffff0000u);
        }
    }

    if (lane < ACT) {
        float sc = inv_in[node];
        unsigned o[NW];
#pragma unroll
        for (int q = 0; q < NW; ++q)
            o[q] = (unsigned)f2b(acc[2 * q] * sc) | ((unsigned)f2b(acc[2 * q + 1] * sc) << 16);
        unsigned* dp = (unsigned*)(agg + (size_t)node * D + off);
        if constexpr (NW == 2) {
            uint2 t; t.x = o[0]; t.y = o[1];
            *(uint2*)dp = t;
        } else {
            *dp = o[0];
        }
    }
}

// ---------------- small tiled GEMM (32->32 and 64->96), bf16 output -------------------
template <int D_IN, int D_OUT, bool SCALE, bool BROW>
__global__ __launch_bounds__(256) void gemm_tile_k(
    const float* __restrict__ in, int in_stride,
    const float* __restrict__ W, const float* __restrict__ bias,
    const float* __restrict__ scale, const float* __restrict__ brow,
    const float* __restrict__ posts,
    u16* __restrict__ out, int out_stride, int n) {
    constexpr int TMW = 8;
    constexpr int ROWS = TMW * 4;
    constexpr int NOUT = (D_OUT + 63) / 64;
    __shared__ float s_in[ROWS * D_IN];

    const int tid = threadIdx.x;
    const int lane = tid & 63;
    const int wave = tid >> 6;
    const int row0 = blockIdx.x * ROWS;

    constexpr int NV = ROWS * D_IN / 4;
    for (int i = tid; i < NV; i += 256) {
        int m = i / (D_IN / 4);
        int kv = i % (D_IN / 4);
        int row = min(row0 + m, n - 1);
        float4 v = *(const float4*)(in + (size_t)row * in_stride + kv * 4);
        if (SCALE) {
            float s = scale[row];
            v.x *= s; v.y *= s; v.z *= s; v.w *= s;
        }
        *(float4*)(s_in + m * D_IN + kv * 4) = v;
    }
    __syncthreads();

    int f[NOUT], ff[NOUT];
    bool fok[NOUT];
    float bv[NOUT];
#pragma unroll
    for (int o = 0; o < NOUT; ++o) {
        f[o] = lane + 64 * o;
        fok[o] = (f[o] < D_OUT);
        ff[o] = fok[o] ? f[o] : 0;
        bv[o] = bias[ff[o]];
    }

    const float* s_my = s_in + wave * TMW * D_IN;

    float acc[NOUT][TMW];
#pragma unroll
    for (int o = 0; o < NOUT; ++o)
#pragma unroll
        for (int m = 0; m < TMW; ++m) acc[o][m] = 0.0f;

    for (int k = 0; k < D_IN; k += 4) {
        float w[4][NOUT];
#pragma unroll
        for (int j = 0; j < 4; ++j)
#pragma unroll
            for (int o = 0; o < NOUT; ++o) w[j][o] = W[(k + j) * D_OUT + ff[o]];
#pragma unroll
        for (int m = 0; m < TMW; ++m) {
            float4 a = *(const float4*)(s_my + m * D_IN + k);
#pragma unroll
            for (int o = 0; o < NOUT; ++o) {
                acc[o][m] = fmaf(a.x, w[0][o], acc[o][m]);
                acc[o][m] = fmaf(a.y, w[1][o], acc[o][m]);
                acc[o][m] = fmaf(a.z, w[2][o], acc[o][m]);
                acc[o][m] = fmaf(a.w, w[3][o], acc[o][m]);
            }
        }
    }

#pragma unroll
    for (int m = 0; m < TMW; ++m) {
        int row = row0 + wave * TMW + m;
        if (row < n) {
            float bc = BROW ? brow[row] : 1.0f;
            float pm = posts[row];
#pragma unroll
            for (int o = 0; o < NOUT; ++o) {
                if (!fok[o]) continue;
                float v = fmaxf(acc[o][m] + bv[o] * bc, 0.0f) * pm;
                out[(size_t)row * out_stride + f[o]] = f2b(v);
            }
        }
    }
}

// ---------------- pack W (fp32 [K][192]) into MFMA B-fragment order, bf16 ---------------
template <int K>
__global__ void pack_w_k(const float* __restrict__ W, u16* __restrict__ Wp) {
    constexpr int KS = K / 32;
    int idx = blockIdx.x * 256 + threadIdx.x;
    if (idx >= 12 * KS * 64) return;
    int l = idx & 63;
    int s = (idx >> 6) % KS;
    int t = (idx >> 6) / KS;
    int col = t * 16 + (l & 15);
    int krow = s * 32 + ((l >> 4) * 8);
    u16 tmp[8] __attribute__((aligned(16)));
#pragma unroll
    for (int j = 0; j < 8; ++j) tmp[j] = f2b(W[(size_t)(krow + j) * 192 + col]);
    *(uint4*)(Wp + (size_t)idx * 8) = *(const uint4*)tmp;
}

// ---------------- MFMA GEMM (conv0): h1 = bf16( relu(A@W + b) * inv_out ) ----------------
template <int K>
__global__ __launch_bounds__(256) void mfma_gemm_k(
    const u16* __restrict__ A, const u16* __restrict__ Wp,
    const float* __restrict__ bias, const float* __restrict__ posts,
    u16* __restrict__ outB, int n) {
    constexpr int KS = K / 32;
    const int tid = threadIdx.x;
    const int lane = tid & 63;
    const int w = tid >> 6;
    const int row0 = blockIdx.x * 16;
    const int arow = row0 + (lane & 15);
    const int kbase = (lane >> 4) * 8;

    f4_t acc[3];
#pragma unroll
    for (int o = 0; o < 3; ++o) acc[o] = (f4_t){0.f, 0.f, 0.f, 0.f};

    const u16* ap = A + (size_t)arow * K + kbase;
#pragma unroll
    for (int s = 0; s < KS; ++s) {
        bf8_t af = *(const bf8_t*)(ap + s * 32);
#pragma unroll
        for (int o = 0; o < 3; ++o) {
            int t = w * 3 + o;
            bf8_t bf = *(const bf8_t*)(Wp + (size_t)((t * KS + s) * 64 + lane) * 8);
            acc[o] = __builtin_amdgcn_mfma_f32_16x16x32_bf16(af, bf, acc[o], 0, 0, 0);
        }
    }

    const int drow = row0 + (lane >> 4) * 4;
    const int dcol = lane & 15;
    float pm[4];
#pragma unroll
    for (int r = 0; r < 4; ++r) pm[r] = posts[drow + r];
#pragma unroll
    for (int o = 0; o < 3; ++o) {
        int col = (w * 3 + o) * 16 + dcol;
        float bv = bias[col];
#pragma unroll
        for (int r = 0; r < 4; ++r) {
            float v = fmaxf(acc[o][r] + bv, 0.0f) * pm[r];
            outB[(size_t)(drow + r) * 192 + col] = f2b(v);
        }
    }
}

// ---------------- fused MFMA: conv1 GEMM + linear GEMM + head (192->192->192->2) ---------
__global__ __launch_bounds__(256) void mfma_fused_k(
    const u16* __restrict__ A,  // [n,192] bf16 (inv_in pre-scaled)
    const u16* __restrict__ Wp1, const float* __restrict__ b1,
    const u16* __restrict__ Wp2, const float* __restrict__ b2,
    const float* __restrict__ Wo, const float* __restrict__ bo,
    float* __restrict__ out, int n) {
    constexpr int KS = 6;       // 192/32
    constexpr int S = 200;      // LDS row stride
    __shared__ float sbuf[16 * S];
    __shared__ float s_head[16][17][2];

    const int tid = threadIdx.x;
    const int lane = tid & 63;
    const int w = tid >> 6;
    const int row0 = blockIdx.x * 16;
    const int arow = row0 + (lane & 15);
    const int kbase = (lane >> 4) * 8;
    const int drow = (lane >> 4) * 4;
    const int dcol = lane & 15;

    f4_t acc[3];
#pragma unroll
    for (int o = 0; o < 3; ++o) acc[o] = (f4_t){0.f, 0.f, 0.f, 0.f};

    // ---- GEMM 1: A (global bf16) @ W1 ----
    const u16* ap = A + (size_t)arow * 192 + kbase;
#pragma unroll
    for (int s = 0; s < KS; ++s) {
        bf8_t af = *(const bf8_t*)(ap + s * 32);
#pragma unroll
        for (int o = 0; o < 3; ++o) {
            int t = w * 3 + o;
            bf8_t bf = *(const bf8_t*)(Wp1 + (size_t)((t * KS + s) * 64 + lane) * 8);
            acc[o] = __builtin_amdgcn_mfma_f32_16x16x32_bf16(af, bf, acc[o], 0, 0, 0);
        }
    }

    // h2 = relu(acc + b1) -> LDS (bf16)
    u16* h2 = (u16*)sbuf;
#pragma unroll
    for (int o = 0; o < 3; ++o) {
        int col = (w * 3 + o) * 16 + dcol;
        float bv = b1[col];
#pragma unroll
        for (int r = 0; r < 4; ++r)
            h2[(drow + r) * S + col] = f2b(fmaxf(acc[o][r] + bv, 0.0f));
    }
    __syncthreads();

    // ---- GEMM 2: h2 (LDS bf16) @ W2 ----
#pragma unroll
    for (int o = 0; o < 3; ++o) acc[o] = (f4_t){0.f, 0.f, 0.f, 0.f};
    const u16* hp = h2 + (lane & 15) * S + kbase;
#pragma unroll
    for (int s = 0; s < KS; ++s) {
        bf8_t af = *(const bf8_t*)(hp + s * 32);
#pragma unroll
        for (int o = 0; o < 3; ++o) {
            int t = w * 3 + o;
            bf8_t bf = *(const bf8_t*)(Wp2 + (size_t)((t * KS + s) * 64 + lane) * 8);
            acc[o] = __builtin_amdgcn_mfma_f32_16x16x32_bf16(af, bf, acc[o], 0, 0, 0);
        }
    }
    __syncthreads();  // all h2 reads done before overwriting sbuf as f32

    // h3 = relu(acc + b2) -> LDS (f32)
#pragma unroll
    for (int o = 0; o < 3; ++o) {
        int col = (w * 3 + o) * 16 + dcol;
        float bv = b2[col];
#pragma unroll
        for (int r = 0; r < 4; ++r)
            sbuf[(drow + r) * S + col] = fmaxf(acc[o][r] + bv, 0.0f);
    }
    __syncthreads();

    // ---- head: out = h3 @ Wo + bo ----
    {
        int r = tid >> 4;
        int seg = tid & 15;
        const float* hr = sbuf + r * S + seg * 12;
        const float* wor = Wo + seg * 24;
        float p0 = 0.0f, p1 = 0.0f;
#pragma unroll
        for (int c = 0; c < 12; ++c) {
            float hv = hr[c];
            p0 = fmaf(hv, wor[c * 2 + 0], p0);
            p1 = fmaf(hv, wor[c * 2 + 1], p1);
        }
        s_head[r][seg][0] = p0;
        s_head[r][seg][1] = p1;
    }
    __syncthreads();
    if (tid < 32) {
        int r = tid >> 1, c = tid & 1;
        float sum = bo[c];
#pragma unroll
        for (int g = 0; g < 16; ++g) sum += s_head[r][g][c];
        int row = row0 + r;
        if (row < n) out[(size_t)row * 2 + c] = sum;
    }
}

extern "C" void kernel_launch(void* const* d_in, const int* in_sizes, int n_in,
                              void* d_out, int out_size, void* d_ws, size_t ws_size,
                              hipStream_t stream) {
    const float* node_feats = (const float*)d_in[0];   // [N,64]
    const float* edge_feats = (const float*)d_in[1];   // [E,32]
    const float* Wn  = (const float*)d_in[2];          // [64,96]
    const float* bn  = (const float*)d_in[3];
    const float* We  = (const float*)d_in[4];          // [32,32]
    const float* be  = (const float*)d_in[5];
    const float* Wc0 = (const float*)d_in[6];          // [128,192]
    const float* bc0 = (const float*)d_in[7];
    const float* Wc1 = (const float*)d_in[8];          // [192,192]
    const float* bc1 = (const float*)d_in[9];
    const float* Wl0 = (const float*)d_in[10];         // [192,192]
    const float* bl0 = (const float*)d_in[11];
    const float* Wo  = (const float*)d_in[12];         // [192,2]
    const float* bo  = (const float*)d_in[13];
    const int* src = (const int*)d_in[14];
    const int* dst = (const int*)d_in[15];
    float* out = (float*)d_out;

    const int N = NN, E = NE;

    // ---- workspace layout (16B-aligned sections) ----
    int* din       = (int*)d_ws;               // N (zeroed) -> cursor_in / deg_in
    int* dout      = din + N;                  // N (zeroed) -> deg_out
    int2* csr      = (int2*)(dout + N);        // CAP*N pairs {src, eid} (padded CSR)
    float* inv_in   = (float*)(csr + (size_t)CAP * N);  // N
    float* inv_out  = inv_in + N;              // N
    float* inv_mean = inv_out + N;             // N
    float* bcoef    = inv_mean + N;            // N
    float* efa      = bcoef + N;               // 32N
    u16* h0   = (u16*)(efa + (size_t)32 * N);  // [N,128] bf16 (x inv_out)
    u16* aggA = h0 + (size_t)128 * N;          // [N,128] bf16 (x inv_in)
    u16* h1   = aggA + (size_t)128 * N;        // [N,192] bf16 (x inv_out)
    u16* aggB = h1 + (size_t)192 * N;          // [N,192] bf16 (x inv_in)
    u16* Wp0  = aggB + (size_t)192 * N;        // 128*192
    u16* Wp1  = Wp0 + 128 * 192;               // 192*192
    u16* Wp2  = Wp1 + 192 * 192;               // 192*192

    hipMemsetAsync(d_ws, 0, (size_t)2 * N * sizeof(int), stream);

    const int GB32 = (N + 31) / 32;   // small-GEMM grid
    const int GB16 = N / 16;          // mfma grid (3125, exact)
    const int GW4  = (N + 3) / 4;     // wave-per-node gather grid (12500)

    // weight packing (tiny, every launch)
    pack_w_k<128><<<dim3(12), dim3(256), 0, stream>>>(Wc0, Wp0);
    pack_w_k<192><<<dim3(18), dim3(256), 0, stream>>>(Wc1, Wp1);
    pack_w_k<192><<<dim3(18), dim3(256), 0, stream>>>(Wl0, Wp2);

    // one-pass build: padded CSR + deg_out
    build_k<<<dim3((E + 255) / 256), dim3(256), 0, stream>>>(src, dst, din, dout, csr, E);
    make_inv_k<<<dim3((N + 255) / 256), dim3(256), 0, stream>>>(din, dout, inv_in, inv_out,
                                                                inv_mean, bcoef, N);

    // edge aggregation: efa = segment_sum(edge_feats, dst)  (fp32)
    gather_e2_k<<<dim3(GW4), dim3(256), 0, stream>>>(edge_feats, csr, din, efa);
    // h0[:,0:32] = bf16( relu((efa*inv_mean)@We + bcoef*be) * inv_out )
    gemm_tile_k<32, 32, true, true><<<dim3(GB32), dim3(256), 0, stream>>>(
        efa, 32, We, be, inv_mean, bcoef, inv_out, h0, 128, N);
    // h0[:,32:128] = bf16( relu(node_feats@Wn + bn) * inv_out )
    gemm_tile_k<64, 96, false, false><<<dim3(GB32), dim3(256), 0, stream>>>(
        node_feats, 64, Wn, bn, nullptr, nullptr, inv_out, h0 + 32, 128, N);

    // conv0: bf16 gather h0 -> aggA (x inv_in), MFMA GEMM 128->192 -> h1 (x inv_out)
    gather_b2_k<128, 2><<<dim3(GW4), dim3(256), 0, stream>>>(h0, csr, din, inv_in, aggA);
    mfma_gemm_k<128><<<dim3(GB16), dim3(256), 0, stream>>>(aggA, Wp0, bc0, inv_out, h1, N);

    // conv1: bf16 gather h1 -> aggB (x inv_in), fused MFMA (conv1 + linear + head) -> out
    gather_b2_k<192, 4><<<dim3(GW4), dim3(256), 0, stream>>>(h1, csr, din, inv_in, aggB);
    mfma_fused_k<<<dim3(GB16), dim3(256), 0, stream>>>(aggB, Wp1, bc1, Wp2, bl0, Wo, bo,
                                                       out, N);
}